// Round 5
// baseline (350.547 us; speedup 1.0000x reference)
//
#include <hip/hip_runtime.h>

#define N_NODES 59392
#define N_EDGES 1187840
#define F_IN 116
#define F_HID 64
#define BATCH 512
#define NPG 116     // nodes per graph
#define ECAPX 20    // per-XCD bucket segment capacity (in-deg/XCD ~ Poisson(2.5))
#define SEG (8 * ECAPX)   // 160 u16 per node in the split edge buffer
#define CCAP 64     // compact bucket: 64 u16 = one 128B line per node

__device__ __forceinline__ int xcc_id() {
    int x;
    asm volatile("s_getreg_b32 %0, hwreg(HW_REG_XCC_ID, 0, 4)" : "=s"(x));
    return x & 7;
}

// ---------------------------------------------------------------- fused edge-pass + gemm1
// Atomics are WORKGROUP scope into per-XCD partial arrays: the RMW executes in the
// XCD-local L2 (no sc1 -> no memory-side 32B write-through stream). Correct because
// partial[k] is only ever touched by blocks whose XCC_ID == k; end-of-kernel release
// writes dirty L2 lines back (same visibility path as plain stores).
__global__ __launch_bounds__(256) void build_gemm1_kernel(const int* __restrict__ src,
                                                          const int* __restrict__ dst,
                                                          unsigned* __restrict__ pout,
                                                          unsigned* __restrict__ pcur,
                                                          unsigned short* __restrict__ ebuf8,
                                                          const float* __restrict__ feat,
                                                          const float* __restrict__ W1,
                                                          float* __restrict__ A1) {
    // ---- edge phase (grid 4640*256 == N_EDGES exactly)
    {
        int xcd = xcc_id();
        unsigned* my_out = pout + xcd * N_NODES;
        unsigned* my_cur = pcur + xcd * N_NODES;
        int e = blockIdx.x * 256 + threadIdx.x;
        int s = src[e], d = dst[e];
        __hip_atomic_fetch_add(&my_out[s], 1u, __ATOMIC_RELAXED, __HIP_MEMORY_SCOPE_WORKGROUP);
        unsigned pos = __hip_atomic_fetch_add(&my_cur[d], 1u, __ATOMIC_RELAXED, __HIP_MEMORY_SCOPE_WORKGROUP);
        if (pos < ECAPX) ebuf8[(size_t)d * SEG + xcd * ECAPX + pos] = (unsigned short)s;
    }
    // ---- gemm phase: A1 = feat @ W1 (onorm deferred into gather — linearity)
    __shared__ float Ws[F_IN][F_HID];   // 29.7 KB
    __shared__ float fs[4][F_IN];
    for (int i = threadIdx.x; i < F_IN * F_HID; i += 256)
        Ws[i / F_HID][i % F_HID] = W1[i];
    int wave = threadIdx.x >> 6;
    int lane = threadIdx.x & 63;
    const int ngroups = N_NODES / 4;    // 14848, exact
    for (int g = blockIdx.x; g < ngroups; g += gridDim.x) {
        int base = g * 4;
        __syncthreads();  // Ws ready (first iter) / fs consumed (later iters)
        for (int i = threadIdx.x; i < 4 * F_IN; i += 256) {
            int r = i / F_IN, k = i - r * F_IN;
            fs[r][k] = feat[(base + r) * F_IN + k];
        }
        __syncthreads();
        int node = base + wave;
        float a0 = 0.f, a1 = 0.f, a2 = 0.f, a3 = 0.f;
        #pragma unroll
        for (int k = 0; k < F_IN; k += 4) {  // 116 % 4 == 0
            a0 += fs[wave][k + 0] * Ws[k + 0][lane];
            a1 += fs[wave][k + 1] * Ws[k + 1][lane];
            a2 += fs[wave][k + 2] * Ws[k + 2][lane];
            a3 += fs[wave][k + 3] * Ws[k + 3][lane];
        }
        A1[node * F_HID + lane] = (a0 + a1) + (a2 + a3);
    }
}

// ---------------------------------------------------------------- norms + bucket compaction
// Sums the 8 per-XCD partials (true degrees for the norms) and compacts the 8
// bucket segments into one contiguous 128B-line bucket per node.
__global__ __launch_bounds__(256) void norm_compact_kernel(const unsigned* __restrict__ pout,
                                                           const unsigned* __restrict__ pcur,
                                                           const unsigned short* __restrict__ ebuf8,
                                                           float* __restrict__ onorm,
                                                           float* __restrict__ inorm,
                                                           int* __restrict__ ncnt,
                                                           unsigned short* __restrict__ cbuf) {
    int i = blockIdx.x * 256 + threadIdx.x;
    if (i >= N_NODES) return;
    int o = 0, c = 0;
    #pragma unroll
    for (int k = 0; k < 8; ++k) {
        o += pout[k * N_NODES + i];
        c += pcur[k * N_NODES + i];
    }
    onorm[i] = rsqrtf(fmaxf((float)o, 1.0f));
    inorm[i] = rsqrtf(fmaxf((float)c, 1.0f));
    const unsigned short* sp = ebuf8 + (size_t)i * SEG;
    unsigned short* dp = cbuf + (size_t)i * CCAP;
    int pos = 0;
    #pragma unroll
    for (int k = 0; k < 8; ++k) {
        int n = pcur[k * N_NODES + i];
        n = n < ECAPX ? n : ECAPX;
        for (int j = 0; j < n && pos < CCAP; ++j) dp[pos++] = sp[k * ECAPX + j];
    }
    ncnt[i] = pos;
}

// ---------------------------------------------------------------- fused gather1 + gemm2
// Per node v (one wave, lane = feature):
//   m    = sum_{u->v} onorm[u] * A1[u]
//   h    = relu(inorm[v]*m + b1) * onorm[v]
//   A2[v]= h @ W2   (shfl broadcast of h x per-lane W2 column)
__global__ __launch_bounds__(256) void layer2_kernel(const int* __restrict__ ncnt,
                                                     const unsigned short* __restrict__ cbuf,
                                                     const float* __restrict__ A1,
                                                     const float* __restrict__ onorm,
                                                     const float* __restrict__ inorm,
                                                     const float* __restrict__ b1,
                                                     const float* __restrict__ W2,
                                                     float* __restrict__ A2) {
    int lane = threadIdx.x & 63;
    float w2[F_HID];                       // W2 column `lane`, in VGPRs
    #pragma unroll
    for (int k = 0; k < F_HID; ++k) w2[k] = W2[k * F_HID + lane];
    float b1l = b1[lane];
    int wid = (blockIdx.x * 256 + threadIdx.x) >> 6;
    int nwaves = (gridDim.x * 256) >> 6;
    for (int v = wid; v < N_NODES; v += nwaves) {
        int n = ncnt[v];
        const unsigned short* eb = cbuf + (size_t)v * CCAP;
        float a0 = 0.f, a1 = 0.f, a2 = 0.f, a3 = 0.f;
        int j = 0;
        for (; j + 3 < n; j += 4) {
            unsigned long long p = *(const unsigned long long*)(eb + j);  // 4 indices
            int u0 = (int)(p & 0xFFFF), u1 = (int)((p >> 16) & 0xFFFF);
            int u2 = (int)((p >> 32) & 0xFFFF), u3 = (int)(p >> 48);
            a0 += onorm[u0] * A1[u0 * F_HID + lane];
            a1 += onorm[u1] * A1[u1 * F_HID + lane];
            a2 += onorm[u2] * A1[u2 * F_HID + lane];
            a3 += onorm[u3] * A1[u3 * F_HID + lane];
        }
        for (; j < n; ++j) { int u = eb[j]; a0 += onorm[u] * A1[u * F_HID + lane]; }
        float m = (a0 + a1) + (a2 + a3);
        float h = fmaxf(inorm[v] * m + b1l, 0.f) * onorm[v];
        float c0 = 0.f, c1 = 0.f, c2 = 0.f, c3 = 0.f;
        #pragma unroll
        for (int k = 0; k < F_HID; k += 4) {
            c0 += __shfl(h, k + 0) * w2[k + 0];
            c1 += __shfl(h, k + 1) * w2[k + 1];
            c2 += __shfl(h, k + 2) * w2[k + 2];
            c3 += __shfl(h, k + 3) * w2[k + 3];
        }
        A2[(size_t)v * F_HID + lane] = (c0 + c1) + (c2 + c3);
    }
}

// ---------------------------------------------------------------- fused gather2 + readout
__global__ __launch_bounds__(1024) void readout_kernel(const int* __restrict__ ncnt,
                                                       const unsigned short* __restrict__ cbuf,
                                                       const float* __restrict__ A2,
                                                       const float* __restrict__ inorm,
                                                       const float* __restrict__ b2,
                                                       const float* __restrict__ Wc,
                                                       const float* __restrict__ bc,
                                                       float* __restrict__ out) {
    int g = blockIdx.x;
    int wave = threadIdx.x >> 6, lane = threadIdx.x & 63;
    float b2l = b2[lane];
    float s0 = 0.f, s1 = 0.f;
    for (int nl = wave; nl < NPG; nl += 16) {
        int v = g * NPG + nl;
        int n = ncnt[v];
        const unsigned short* eb = cbuf + (size_t)v * CCAP;
        float a0 = 0.f, a1 = 0.f, a2 = 0.f, a3 = 0.f;
        int j = 0;
        for (; j + 3 < n; j += 4) {
            unsigned long long p = *(const unsigned long long*)(eb + j);
            int u0 = (int)(p & 0xFFFF), u1 = (int)((p >> 16) & 0xFFFF);
            int u2 = (int)((p >> 32) & 0xFFFF), u3 = (int)(p >> 48);
            a0 += A2[u0 * F_HID + lane];
            a1 += A2[u1 * F_HID + lane];
            a2 += A2[u2 * F_HID + lane];
            a3 += A2[u3 * F_HID + lane];
        }
        for (; j < n; ++j) a0 += A2[eb[j] * F_HID + lane];
        float m = (a0 + a1) + (a2 + a3);
        float h = fmaxf(inorm[v] * m + b2l, 0.f);
        float2 w = ((const float2*)Wc)[nl * F_HID + lane];
        s0 += h * w.x;
        s1 += h * w.y;
    }
    #pragma unroll
    for (int off = 32; off > 0; off >>= 1) {
        s0 += __shfl_down(s0, off);
        s1 += __shfl_down(s1, off);
    }
    __shared__ float ls[32];
    if (lane == 0) { ls[wave * 2] = s0; ls[wave * 2 + 1] = s1; }
    __syncthreads();
    if (threadIdx.x < 2) {
        float t = 0.f;
        #pragma unroll
        for (int w = 0; w < 16; ++w) t += ls[w * 2 + threadIdx.x];
        out[g * 2 + threadIdx.x] = t + bc[threadIdx.x];
    }
}

extern "C" void kernel_launch(void* const* d_in, const int* in_sizes, int n_in,
                              void* d_out, int out_size, void* d_ws, size_t ws_size,
                              hipStream_t stream) {
    const float* feat = (const float*)d_in[0];
    const int*   src  = (const int*)d_in[1];
    const int*   dst  = (const int*)d_in[2];
    // d_in[3] = batch_size (fixed 512)
    const float* W1 = (const float*)d_in[4];
    const float* b1 = (const float*)d_in[5];
    const float* W2 = (const float*)d_in[6];
    const float* b2 = (const float*)d_in[7];
    const float* Wc = (const float*)d_in[8];
    const float* bc = (const float*)d_in[9];
    float* out = (float*)d_out;

    // ws layout (≈44.2 MiB, all offsets 128B-aligned):
    // pout[8N] pcur[8N] (u32) | onorm[N] inorm[N] (f32) | ncnt[N] (i32)
    // | cbuf u16[N*CCAP] | A1 f32[N*64] | { ebuf8 u16[N*SEG]  ALIASED WITH  A2 f32[N*64] }
    // (ebuf8 is dead after norm_compact; A2 is first written by layer2 — safe alias)
    unsigned* pout = (unsigned*)d_ws;
    unsigned* pcur = pout + (size_t)8 * N_NODES;
    float* onorm = (float*)(pcur + (size_t)8 * N_NODES);
    float* inorm = onorm + N_NODES;
    int* ncnt    = (int*)(inorm + N_NODES);
    unsigned short* cbuf = (unsigned short*)(ncnt + N_NODES);
    float* A1    = (float*)(cbuf + (size_t)N_NODES * CCAP);
    unsigned short* ebuf8 = (unsigned short*)(A1 + (size_t)N_NODES * F_HID);
    float* A2    = (float*)ebuf8;

    hipMemsetAsync(pout, 0, (size_t)16 * N_NODES * sizeof(unsigned), stream);

    build_gemm1_kernel<<<N_EDGES / 256, 256, 0, stream>>>(src, dst, pout, pcur, ebuf8,
                                                          feat, W1, A1);
    norm_compact_kernel<<<(N_NODES + 255) / 256, 256, 0, stream>>>(pout, pcur, ebuf8,
                                                                   onorm, inorm, ncnt, cbuf);
    layer2_kernel<<<2048, 256, 0, stream>>>(ncnt, cbuf, A1, onorm, inorm, b1, W2, A2);
    readout_kernel<<<BATCH, 1024, 0, stream>>>(ncnt, cbuf, A2, inorm, b2, Wc, bc, out);
}